// Round 9
// baseline (291.980 us; speedup 1.0000x reference)
//
#include <hip/hip_runtime.h>
#include <cstdint>
#include <cstddef>

typedef float  f32x4 __attribute__((ext_vector_type(4)));
typedef float  f32x2 __attribute__((ext_vector_type(2)));
typedef short  s16x8 __attribute__((ext_vector_type(8)));
typedef short  s16x4 __attribute__((ext_vector_type(4)));
typedef unsigned int u32x4 __attribute__((ext_vector_type(4)));

#define EPSV 1e-5f

__device__ __forceinline__ float rfl(float v) {
  return __builtin_bit_cast(float, __builtin_amdgcn_readfirstlane(__builtin_bit_cast(int, v)));
}
__device__ __forceinline__ unsigned pk2(float a, float b) {
  unsigned short ua = __builtin_bit_cast(unsigned short, (__bf16)a);
  unsigned short ub = __builtin_bit_cast(unsigned short, (__bf16)b);
  return (unsigned)ua | ((unsigned)ub << 16);
}
__device__ __forceinline__ void gll16(const void* g, void* l) {
  __builtin_amdgcn_global_load_lds((const __attribute__((address_space(1))) unsigned int*)g,
                                   (__attribute__((address_space(3))) unsigned int*)l, 16, 0, 0);
}

// ---------------- kernel F: fold BN-o into Wo, emit bf16 in fragment layout ----------------
__global__ void kF(const float* __restrict__ wo, const float* __restrict__ bo,
                   const float* __restrict__ go, const float* __restrict__ beo,
                   const float* __restrict__ mo, const float* __restrict__ vo,
                   __bf16* __restrict__ wopp, float* __restrict__ co)
{
  const int oc = blockIdx.x;   // 0..511
  const int k  = threadIdx.x;  // 0..511
  float invo = go[oc] * rsqrtf(vo[oc] + EPSV);
  float v = wo[(size_t)oc*512 + k] * invo;
  int mt = oc >> 7, ocl = oc & 127;
  int kt = k >> 6, kk = (k >> 5) & 1, g = (k >> 3) & 3, jj = k & 7;
  size_t dst = (size_t)(mt*8 + kt)*10240 + (size_t)kk*5120 + ocl*40 + g*8 + jj;
  wopp[dst] = (__bf16)v;
  if (k == 0) co[oc] = bo[oc]*invo + beo[oc] - mo[oc]*invo;
}

// ---------------- kernel A: 4 dilated depthwise convs + BN + ReLU + 4x4 mix + BN + ReLU ----
// block = (b, c, half-plane): 768 thr, 48 output rows, 6 px/thread (16 colg x 48 rows).
// LDS: 84 rows x 118 f32 padded layout (18-col left pad, 4-col slack, zero halo rows) ->
// no masks, no range checks, conflict-free b64 reads (R6-validated: 786K conflicts).
// 6 px/thread halves live state vs R8 (zacc 24 f32, acc 6, windows <=10): fits the 85-VGPR
// cap of (768,6) with margin -- R6/R7/R8 spilled because live ~110-130 exceeded every cap.
// sched_barrier(0) at each phase top stops staging loads hoisting across phases.
__global__ __launch_bounds__(768, 6) void kA(const float* __restrict__ x,
    const float* __restrict__ wdw, const float* __restrict__ bdw, const float* __restrict__ gdw,
    const float* __restrict__ bedw, const float* __restrict__ mdw, const float* __restrict__ vdw,
    const float* __restrict__ w4, const float* __restrict__ bsc, const float* __restrict__ gsc,
    const float* __restrict__ besc, const float* __restrict__ msc, const float* __restrict__ vsc,
    __bf16* __restrict__ z2s)
{
  __shared__ alignas(16) float sp[9932];        // 84*118 + 20 slack = 39728 B
  const int tid = threadIdx.x;
  const int bc = blockIdx.x >> 1, half = blockIdx.x & 1;
  const int b = bc >> 7, c = bc & 127;
  const int h0 = half * 48;
  const int gstart = half ? 30 : 0;             // staged global rows [gstart, gstart+66)
  const int Lb     = half ? 0 : 18;             // LDS row of first staged global row

  // uniform folded params (readfirstlane -> SGPRs)
  float wf[4][9], cdwv[4], w4f[4][4], c4v[4];
  #pragma unroll
  for (int i = 0; i < 4; ++i) {
    int idx = i*128 + c;
    float inv = gdw[idx] * rsqrtf(vdw[idx] + EPSV);
    #pragma unroll
    for (int t = 0; t < 9; ++t) wf[i][t] = rfl(wdw[(size_t)idx*9 + t] * inv);
    cdwv[i] = rfl(bdw[idx]*inv + bedw[idx] - mdw[idx]*inv);
  }
  #pragma unroll
  for (int o = 0; o < 4; ++o) {
    float invs = gsc[o] * rsqrtf(vsc[o] + EPSV);
    #pragma unroll
    for (int i = 0; i < 4; ++i) w4f[o][i] = rfl(w4[o*4 + i] * invs);
    c4v[o] = rfl(bsc[o]*invs + besc[o] - msc[o]*invs);
  }

  { // zero whole buffer incl. slack (stage writes only interior cols -> pads persist)
    f32x2* spv = (f32x2*)sp;
    #pragma unroll
    for (int z = 0; z < 7; ++z) {
      int idx = tid + z*768;
      if (idx < 4966) spv[idx] = (f32x2){0.f, 0.f};
    }
  }

  const int colg = tid & 15, rowt = tid >> 4;   // 16 col-groups of 6 px, 48 rows
  const int w0 = colg * 6;
  const f32x4* xv = (const f32x4*)x;
  const size_t gbase = (size_t)(b*512 + c) * 2304;

  f32x2 zacc[4][3];
  #pragma unroll
  for (int o = 0; o < 4; ++o)
    #pragma unroll
    for (int k = 0; k < 3; ++k) zacc[o][k] = (f32x2){c4v[o], c4v[o]};

  const float* base = sp + rowt*118 + 18 + w0;  // output row rowt -> LDS row rowt+18 via R0

  const int RR[4] = {1, 6, 12, 18};
  #pragma unroll
  for (int i = 0; i < 4; ++i) {
    const int r = RR[i];
    __syncthreads();                            // buffer free (zero done / prev compute done)
    __builtin_amdgcn_sched_barrier(0);          // keep this phase's loads in this phase
    #pragma unroll
    for (int k = 0; k < 2; ++k) {               // stage 66 rows x 24 f32x4 = 1584
      int idx = tid + k*768;
      int rr = idx / 24, cc = idx - rr*24;
      f32x4 v = xv[gbase + (size_t)i*294912 + (size_t)((gstart + rr)*24 + cc)];
      float* d = sp + (Lb + rr)*118 + 18 + cc*4;
      *(f32x2*)(d)     = (f32x2){v.x, v.y};
      *(f32x2*)(d + 2) = (f32x2){v.z, v.w};
    }
    if (tid < 48) {
      int idx = tid + 1536;
      int rr = idx / 24, cc = idx - rr*24;
      f32x4 v = xv[gbase + (size_t)i*294912 + (size_t)((gstart + rr)*24 + cc)];
      float* d = sp + (Lb + rr)*118 + 18 + cc*4;
      *(f32x2*)(d)     = (f32x2){v.x, v.y};
      *(f32x2*)(d + 2) = (f32x2){v.z, v.w};
    }
    __syncthreads();                            // plane ready

    f32x2 acc[3];
    #pragma unroll
    for (int k = 0; k < 3; ++k) acc[k] = (f32x2){0.f, 0.f};

    #pragma unroll
    for (int d = 0; d < 3; ++d) {               // dh = d-1; all ds offsets compile-time
      const int R0 = (18 + (d-1)*r)*118;        // row delta relative to `base`
      const float wl = wf[i][d*3], wc = wf[i][d*3+1], wr = wf[i][d*3+2];
      if (i == 0) {                              // r=1: span [w0-2, w0+8) = 5 native f32x2
        f32x2 s0 = *(const f32x2*)(base + R0 - 2);
        f32x2 s1 = *(const f32x2*)(base + R0);
        f32x2 s2 = *(const f32x2*)(base + R0 + 2);
        f32x2 s3 = *(const f32x2*)(base + R0 + 4);
        f32x2 s4 = *(const f32x2*)(base + R0 + 6);
        // px j: tl=col w0+j-1, tc=w0+j, tr=w0+j+1
        acc[0].x += wl*s0.y + wc*s1.x + wr*s1.y;
        acc[0].y += wl*s1.x + wc*s1.y + wr*s2.x;
        acc[1].x += wl*s1.y + wc*s2.x + wr*s2.y;
        acc[1].y += wl*s2.x + wc*s2.y + wr*s3.x;
        acc[2].x += wl*s2.y + wc*s3.x + wr*s3.y;
        acc[2].y += wl*s3.x + wc*s3.y + wr*s4.x;
      } else {                                   // even r: 3 windows of 3 f32x2, rolled
        f32x2 t0, t1, t2;
        t0 = *(const f32x2*)(base + R0 - r);
        t1 = *(const f32x2*)(base + R0 - r + 2);
        t2 = *(const f32x2*)(base + R0 - r + 4);
        acc[0] += wl*t0; acc[1] += wl*t1; acc[2] += wl*t2;
        t0 = *(const f32x2*)(base + R0);
        t1 = *(const f32x2*)(base + R0 + 2);
        t2 = *(const f32x2*)(base + R0 + 4);
        acc[0] += wc*t0; acc[1] += wc*t1; acc[2] += wc*t2;
        t0 = *(const f32x2*)(base + R0 + r);
        t1 = *(const f32x2*)(base + R0 + r + 2);
        t2 = *(const f32x2*)(base + R0 + r + 4);
        acc[0] += wr*t0; acc[1] += wr*t1; acc[2] += wr*t2;
      }
    }
    #pragma unroll
    for (int k = 0; k < 3; ++k) {
      f32x2 y;
      y.x = fmaxf(acc[k].x + cdwv[i], 0.f);
      y.y = fmaxf(acc[k].y + cdwv[i], 0.f);
      #pragma unroll
      for (int o = 0; o < 4; ++o) zacc[o][k] += w4f[o][i] * y;
    }
  }

  // finalize + store: [pix][o]; thread owns 6 px = 48 B contiguous (16B-aligned)
#define ZG(o, k, j) fmaxf((j) ? zacc[o][k].y : zacc[o][k].x, 0.f)
  const int h = h0 + rowt;
  u32x4* dst = (u32x4*)(z2s + ((size_t)(b*128 + c)*9216 + (size_t)(h*96 + w0))*4);
  #pragma unroll
  for (int k = 0; k < 3; ++k) {
    u32x4 s = { pk2(ZG(0,k,0), ZG(1,k,0)), pk2(ZG(2,k,0), ZG(3,k,0)),
                pk2(ZG(0,k,1), ZG(1,k,1)), pk2(ZG(2,k,1), ZG(3,k,1)) };
    dst[k] = s;
  }
#undef ZG
}

// ---------------- kernel B: out = ReLU(Wo'' @ z2 + co), bf16 MFMA, m97 structure -----------
__global__ __launch_bounds__(256) void kB(const void* __restrict__ wopp_,
    const void* __restrict__ z2s_, const float* __restrict__ co, float* __restrict__ out)
{
  __shared__ alignas(16) char lA[20480];
  __shared__ alignas(16) char lB[16384];
  const char* wopp = (const char*)wopp_;
  const char* z2s  = (const char*)z2s_;

  const int tid = threadIdx.x;
  const int lane = tid & 63, wv = tid >> 6;
  const int wm = wv >> 1, wn = wv & 1;
  const int pt = blockIdx.x;      // 0..71 pixel tiles
  const int mt = blockIdx.y;      // 0..3  oc tiles
  const int b  = blockIdx.z;      // 0..7
  const int pix0 = pt * 128;
  const int l15 = lane & 15, lg = lane >> 4;

  f32x4 acc[4][4] = {};

  for (int kt = 0; kt < 8; ++kt) {
    const char* srcA = wopp + (size_t)(mt*8 + kt)*20480;
    for (int j = wv; j < 20; j += 4)
      gll16(srcA + j*1024 + lane*16, lA + j*1024);
    #pragma unroll
    for (int ct4 = 0; ct4 < 4; ++ct4) {
      int ct = wv*4 + ct4;
      const char* srcB = z2s + ((size_t)(b*128 + kt*16 + ct)*36864 + (size_t)pix0*4)*2;
      gll16(srcB + lane*16, lB + ct*1024);
    }
    __syncthreads();

    #pragma unroll
    for (int kk = 0; kk < 2; ++kk) {
      s16x8 af[4];
      #pragma unroll
      for (int m = 0; m < 4; ++m)
        af[m] = *(const s16x8*)(lA + kk*10240 + (wm*64 + m*16 + l15)*80 + lg*16);
      #pragma unroll
      for (int n = 0; n < 4; ++n) {
        const char* p = lB + kk*8192 + lg*2048 + (wn*64 + n*16 + l15)*8;
        s16x4 lo = *(const s16x4*)(p);
        s16x4 hi = *(const s16x4*)(p + 1024);
        s16x8 bfr = __builtin_shufflevector(lo, hi, 0,1,2,3,4,5,6,7);
        #pragma unroll
        for (int m = 0; m < 4; ++m)
          acc[m][n] = __builtin_amdgcn_mfma_f32_16x16x32_bf16(af[m], bfr, acc[m][n], 0, 0, 0);
      }
    }
    __syncthreads();
  }

  const int colp = pix0 + wn*64 + l15;
  #pragma unroll
  for (int m = 0; m < 4; ++m) {
    const int ocb = mt*128 + wm*64 + m*16 + lg*4;
    #pragma unroll
    for (int r2 = 0; r2 < 4; ++r2) {
      const int oc = ocb + r2;
      const float cov = co[oc];
      float* orow = out + ((size_t)(b*512 + oc))*9216 + colp;
      #pragma unroll
      for (int n = 0; n < 4; ++n) {
        float v = acc[m][n][r2] + cov;
        orow[(size_t)n*16] = fmaxf(v, 0.f);
      }
    }
  }
}

extern "C" void kernel_launch(void* const* d_in, const int* in_sizes, int n_in,
                              void* d_out, int out_size, void* d_ws, size_t ws_size,
                              hipStream_t stream)
{
  (void)in_sizes; (void)out_size;
  if (n_in < 19) return;
  const size_t Z2_BYTES = 75497472;      // 8*512*9216 bf16
  const size_t WOPP_BYTES = 655360;      // 32 chunks * 20480
  if (ws_size < Z2_BYTES + WOPP_BYTES + 2048) return;

  const float* x    = (const float*)d_in[0];
  const float* wdw  = (const float*)d_in[1];
  const float* bdw  = (const float*)d_in[2];
  const float* gdw  = (const float*)d_in[3];
  const float* bedw = (const float*)d_in[4];
  const float* mdw  = (const float*)d_in[5];
  const float* vdw  = (const float*)d_in[6];
  const float* w4   = (const float*)d_in[7];
  const float* bs   = (const float*)d_in[8];
  const float* gs   = (const float*)d_in[9];
  const float* bes  = (const float*)d_in[10];
  const float* ms   = (const float*)d_in[11];
  const float* vs   = (const float*)d_in[12];
  const float* wo   = (const float*)d_in[13];
  const float* bo   = (const float*)d_in[14];
  const float* go   = (const float*)d_in[15];
  const float* beo  = (const float*)d_in[16];
  const float* mo   = (const float*)d_in[17];
  const float* vo   = (const float*)d_in[18];

  __bf16* z2s  = (__bf16*)d_ws;
  __bf16* wopp = (__bf16*)((char*)d_ws + Z2_BYTES);
  float*  co   = (float*)((char*)d_ws + Z2_BYTES + WOPP_BYTES);

  kF<<<512, 512, 0, stream>>>(wo, bo, go, beo, mo, vo, wopp, co);
  kA<<<2048, 768, 0, stream>>>(x, wdw, bdw, gdw, bedw, mdw, vdw, w4, bs, gs, bes, ms, vs, z2s);
  kB<<<dim3(72, 4, 8), 256, 0, stream>>>(wopp, z2s, co, (float*)d_out);
}

// Round 10
// 124.237 us; speedup vs baseline: 2.3502x; 2.3502x over previous
//
#include <hip/hip_runtime.h>
#include <cstdint>
#include <cstddef>

typedef float  f32x4 __attribute__((ext_vector_type(4)));
typedef float  f32x2 __attribute__((ext_vector_type(2)));
typedef short  s16x8 __attribute__((ext_vector_type(8)));
typedef short  s16x4 __attribute__((ext_vector_type(4)));
typedef unsigned int u32x4 __attribute__((ext_vector_type(4)));

#define EPSV 1e-5f

__device__ __forceinline__ float rfl(float v) {
  return __builtin_bit_cast(float, __builtin_amdgcn_readfirstlane(__builtin_bit_cast(int, v)));
}
__device__ __forceinline__ unsigned pk2(float a, float b) {
  unsigned short ua = __builtin_bit_cast(unsigned short, (__bf16)a);
  unsigned short ub = __builtin_bit_cast(unsigned short, (__bf16)b);
  return (unsigned)ua | ((unsigned)ub << 16);
}
__device__ __forceinline__ void gll16(const void* g, void* l) {
  __builtin_amdgcn_global_load_lds((const __attribute__((address_space(1))) unsigned int*)g,
                                   (__attribute__((address_space(3))) unsigned int*)l, 16, 0, 0);
}
__device__ __forceinline__ f32x4 relu4(f32x4 v) {
  f32x4 r; r.x = fmaxf(v.x,0.f); r.y = fmaxf(v.y,0.f); r.z = fmaxf(v.z,0.f); r.w = fmaxf(v.w,0.f);
  return r;
}

// ---------------- kernel F: fold BN-o into Wo, emit bf16 in fragment layout ----------------
__global__ void kF(const float* __restrict__ wo, const float* __restrict__ bo,
                   const float* __restrict__ go, const float* __restrict__ beo,
                   const float* __restrict__ mo, const float* __restrict__ vo,
                   __bf16* __restrict__ wopp, float* __restrict__ co)
{
  const int oc = blockIdx.x;   // 0..511
  const int k  = threadIdx.x;  // 0..511
  float invo = go[oc] * rsqrtf(vo[oc] + EPSV);
  float v = wo[(size_t)oc*512 + k] * invo;
  int mt = oc >> 7, ocl = oc & 127;
  int kt = k >> 6, kk = (k >> 5) & 1, g = (k >> 3) & 3, jj = k & 7;
  size_t dst = (size_t)(mt*8 + kt)*10240 + (size_t)kk*5120 + ocl*40 + g*8 + jj;
  wopp[dst] = (__bf16)v;
  if (k == 0) co[oc] = bo[oc]*invo + beo[oc] - mo[oc]*invo;
}

// ---------------- kernel A: 4 dilated depthwise convs + BN + ReLU + 4x4 mix + BN + ReLU ----
// EXACTLY R4's clean structure (VGPR 40, zero spill, FETCH/WRITE 74 MB) + ONE delta:
// T14 async-stage split -- plane i+1's 3 f32x4 global loads are issued BEFORE compute of
// plane i (pinned by sched_barrier(0)); only the ds_writes remain between the barriers.
// R6-R9 lesson: restructuring the conv loop makes the allocator spill pathologically
// (0.3-1 GB scratch traffic) regardless of nominal live-set size; do not touch compute.
__global__ __launch_bounds__(768, 6) void kA(const float* __restrict__ x,
    const float* __restrict__ wdw, const float* __restrict__ bdw, const float* __restrict__ gdw,
    const float* __restrict__ bedw, const float* __restrict__ mdw, const float* __restrict__ vdw,
    const float* __restrict__ w4, const float* __restrict__ bsc, const float* __restrict__ gsc,
    const float* __restrict__ besc, const float* __restrict__ msc, const float* __restrict__ vsc,
    __bf16* __restrict__ z2s)
{
  __shared__ alignas(16) float sp[96*136];   // 52224 B: row = 20 pad | 96 data | 20 slack
  const int tid = threadIdx.x;
  const int b = blockIdx.x >> 7, c = blockIdx.x & 127;

  // uniform folded params (readfirstlane -> SGPRs)
  float wf[4][9], cdwv[4], w4f[4][4], c4v[4];
  #pragma unroll
  for (int i = 0; i < 4; ++i) {
    int idx = i*128 + c;
    float inv = gdw[idx] * rsqrtf(vdw[idx] + EPSV);
    #pragma unroll
    for (int t = 0; t < 9; ++t) wf[i][t] = rfl(wdw[(size_t)idx*9 + t] * inv);
    cdwv[i] = rfl(bdw[idx]*inv + bedw[idx] - mdw[idx]*inv);
  }
  #pragma unroll
  for (int o = 0; o < 4; ++o) {
    float invs = gsc[o] * rsqrtf(vsc[o] + EPSV);
    #pragma unroll
    for (int i = 0; i < 4; ++i) w4f[o][i] = rfl(w4[o*4 + i] * invs);
    c4v[o] = rfl(bsc[o]*invs + besc[o] - msc[o]*invs);
  }

  // zero the row pads once (stage writes only touch interior cols 20..115)
  for (int z = tid; z < 96*40; z += 768) {
    int row = z / 40, cw = z - row*40;
    sp[row*136 + (cw < 20 ? cw : 96 + cw)] = 0.f;
  }

  const int wq = tid % 24;
  const int hb = (tid / 24) * 3;      // 32 h-groups * 3 rows = 96, exact
  const int w0 = wq * 4;

  const f32x4* xv = (const f32x4*)x;
  const size_t gbase = (size_t)(b*512 + c) * 2304;   // f32x4 units; +i*294912 per branch

  // stage coords (same as R4): element j = tid + k*768 -> (row, col-quad)
  const int s0r = tid / 24,          s0c = tid - s0r*24;
  const int s1r = (tid + 768) / 24,  s1c = (tid + 768) - s1r*24;
  const int s2r = (tid + 1536) / 24, s2c = (tid + 1536) - s2r*24;
  float* st0 = sp + s0r*136 + 20 + s0c*4;
  float* st1 = sp + s1r*136 + 20 + s1c*4;
  float* st2 = sp + s2r*136 + 20 + s2c*4;

  f32x4 zacc[4][3];
  #pragma unroll
  for (int o = 0; o < 4; ++o)
    #pragma unroll
    for (int k = 0; k < 3; ++k)
      zacc[o][k] = (f32x4){c4v[o], c4v[o], c4v[o], c4v[o]};

  // prologue: stage plane 0 directly
  {
    f32x4 p0 = xv[gbase + tid];
    f32x4 p1 = xv[gbase + tid + 768];
    f32x4 p2 = xv[gbase + tid + 1536];
    *(f32x4*)st0 = p0;
    *(f32x4*)st1 = p1;
    *(f32x4*)st2 = p2;
  }
  __syncthreads();

  const int RR[4] = {1, 6, 12, 18};

  #pragma unroll
  for (int i = 0; i < 4; ++i) {
    // T14: issue next plane's loads BEFORE this plane's compute; latency hides under it
    f32x4 pf0, pf1, pf2;
    if (i < 3) {
      const size_t pb = gbase + (size_t)(i+1)*294912;
      pf0 = xv[pb + tid];
      pf1 = xv[pb + tid + 768];
      pf2 = xv[pb + tid + 1536];
      __builtin_amdgcn_sched_barrier(0);   // pin the loads above the compute
    }

    const int r = RR[i];
    #pragma unroll
    for (int k = 0; k < 3; ++k) {
      const int h = hb + k;
      f32x4 acc = {0.f, 0.f, 0.f, 0.f};
      #pragma unroll
      for (int dh = -1; dh <= 1; ++dh) {
        const int h2 = h + dh*r;
        if ((unsigned)h2 < 96u) {
          const float* row = sp + h2*136 + 20 + w0;
          f32x4 tc = *(const f32x4*)row;      // 16B-aligned
          f32x4 tl, tr;
          if (i == 0) {                        // r=1: two 8B edge reads + register compose
            f32x2 a  = *(const f32x2*)(row - 2);
            f32x2 bb = *(const f32x2*)(row + 4);
            tl = (f32x4){a.y, tc.x, tc.y, tc.z};
            tr = (f32x4){tc.y, tc.z, tc.w, bb.x};
          } else if (r == 12) {                // 16B-aligned
            tl = *(const f32x4*)(row - 12);
            tr = *(const f32x4*)(row + 12);
          } else {                             // r=6/18: 8B-aligned pairs
            f32x2 a0 = *(const f32x2*)(row - r), a1 = *(const f32x2*)(row - r + 2);
            f32x2 b0 = *(const f32x2*)(row + r), b1 = *(const f32x2*)(row + r + 2);
            tl = (f32x4){a0.x, a0.y, a1.x, a1.y};
            tr = (f32x4){b0.x, b0.y, b1.x, b1.y};
          }
          const int wb = (dh + 1) * 3;
          acc += wf[i][wb]*tl + wf[i][wb+1]*tc + wf[i][wb+2]*tr;
        }
      }
      f32x4 y = relu4(acc + cdwv[i]);
      #pragma unroll
      for (int o = 0; o < 4; ++o) zacc[o][k] += w4f[o][i]*y;
    }

    __syncthreads();                           // everyone done reading plane i
    if (i < 3) {
      *(f32x4*)st0 = pf0;                      // writes only; loads long landed
      *(f32x4*)st1 = pf1;
      *(f32x4*)st2 = pf2;
      __syncthreads();                         // plane i+1 ready
    }
  }

  // finalize + store: [pix][o], 16 bf16 = 32B contiguous per quad (R4 verbatim)
  __bf16* zbase = z2s + (size_t)(b*128 + c) * 36864;
  #pragma unroll
  for (int k = 0; k < 3; ++k) {
    const int h = hb + k;
    f32x4 z[4];
    #pragma unroll
    for (int o = 0; o < 4; ++o) z[o] = relu4(zacc[o][k]);
    u32x4 s0 = { pk2(z[0].x,z[1].x), pk2(z[2].x,z[3].x), pk2(z[0].y,z[1].y), pk2(z[2].y,z[3].y) };
    u32x4 s1 = { pk2(z[0].z,z[1].z), pk2(z[2].z,z[3].z), pk2(z[0].w,z[1].w), pk2(z[2].w,z[3].w) };
    u32x4* dst = (u32x4*)(zbase + (size_t)(h*24 + wq)*16);
    dst[0] = s0;
    dst[1] = s1;
  }
}

// ---------------- kernel B: out = ReLU(Wo'' @ z2 + co), bf16 MFMA, m97 structure -----------
__global__ __launch_bounds__(256) void kB(const void* __restrict__ wopp_,
    const void* __restrict__ z2s_, const float* __restrict__ co, float* __restrict__ out)
{
  __shared__ alignas(16) char lA[20480];
  __shared__ alignas(16) char lB[16384];
  const char* wopp = (const char*)wopp_;
  const char* z2s  = (const char*)z2s_;

  const int tid = threadIdx.x;
  const int lane = tid & 63, wv = tid >> 6;
  const int wm = wv >> 1, wn = wv & 1;
  const int pt = blockIdx.x;      // 0..71 pixel tiles
  const int mt = blockIdx.y;      // 0..3  oc tiles
  const int b  = blockIdx.z;      // 0..7
  const int pix0 = pt * 128;
  const int l15 = lane & 15, lg = lane >> 4;

  f32x4 acc[4][4] = {};

  for (int kt = 0; kt < 8; ++kt) {
    const char* srcA = wopp + (size_t)(mt*8 + kt)*20480;
    for (int j = wv; j < 20; j += 4)
      gll16(srcA + j*1024 + lane*16, lA + j*1024);
    #pragma unroll
    for (int ct4 = 0; ct4 < 4; ++ct4) {
      int ct = wv*4 + ct4;
      const char* srcB = z2s + ((size_t)(b*128 + kt*16 + ct)*36864 + (size_t)pix0*4)*2;
      gll16(srcB + lane*16, lB + ct*1024);
    }
    __syncthreads();

    #pragma unroll
    for (int kk = 0; kk < 2; ++kk) {
      s16x8 af[4];
      #pragma unroll
      for (int m = 0; m < 4; ++m)
        af[m] = *(const s16x8*)(lA + kk*10240 + (wm*64 + m*16 + l15)*80 + lg*16);
      #pragma unroll
      for (int n = 0; n < 4; ++n) {
        const char* p = lB + kk*8192 + lg*2048 + (wn*64 + n*16 + l15)*8;
        s16x4 lo = *(const s16x4*)(p);
        s16x4 hi = *(const s16x4*)(p + 1024);
        s16x8 bfr = __builtin_shufflevector(lo, hi, 0,1,2,3,4,5,6,7);
        #pragma unroll
        for (int m = 0; m < 4; ++m)
          acc[m][n] = __builtin_amdgcn_mfma_f32_16x16x32_bf16(af[m], bfr, acc[m][n], 0, 0, 0);
      }
    }
    __syncthreads();
  }

  const int colp = pix0 + wn*64 + l15;
  #pragma unroll
  for (int m = 0; m < 4; ++m) {
    const int ocb = mt*128 + wm*64 + m*16 + lg*4;
    #pragma unroll
    for (int r2 = 0; r2 < 4; ++r2) {
      const int oc = ocb + r2;
      const float cov = co[oc];
      float* orow = out + ((size_t)(b*512 + oc))*9216 + colp;
      #pragma unroll
      for (int n = 0; n < 4; ++n) {
        float v = acc[m][n][r2] + cov;
        orow[(size_t)n*16] = fmaxf(v, 0.f);
      }
    }
  }
}

extern "C" void kernel_launch(void* const* d_in, const int* in_sizes, int n_in,
                              void* d_out, int out_size, void* d_ws, size_t ws_size,
                              hipStream_t stream)
{
  (void)in_sizes; (void)out_size;
  if (n_in < 19) return;
  const size_t Z2_BYTES = 75497472;      // 8*512*9216 bf16
  const size_t WOPP_BYTES = 655360;      // 32 chunks * 20480
  if (ws_size < Z2_BYTES + WOPP_BYTES + 2048) return;

  const float* x    = (const float*)d_in[0];
  const float* wdw  = (const float*)d_in[1];
  const float* bdw  = (const float*)d_in[2];
  const float* gdw  = (const float*)d_in[3];
  const float* bedw = (const float*)d_in[4];
  const float* mdw  = (const float*)d_in[5];
  const float* vdw  = (const float*)d_in[6];
  const float* w4   = (const float*)d_in[7];
  const float* bs   = (const float*)d_in[8];
  const float* gs   = (const float*)d_in[9];
  const float* bes  = (const float*)d_in[10];
  const float* ms   = (const float*)d_in[11];
  const float* vs   = (const float*)d_in[12];
  const float* wo   = (const float*)d_in[13];
  const float* bo   = (const float*)d_in[14];
  const float* go   = (const float*)d_in[15];
  const float* beo  = (const float*)d_in[16];
  const float* mo   = (const float*)d_in[17];
  const float* vo   = (const float*)d_in[18];

  __bf16* z2s  = (__bf16*)d_ws;
  __bf16* wopp = (__bf16*)((char*)d_ws + Z2_BYTES);
  float*  co   = (float*)((char*)d_ws + Z2_BYTES + WOPP_BYTES);

  kF<<<512, 512, 0, stream>>>(wo, bo, go, beo, mo, vo, wopp, co);
  kA<<<1024, 768, 0, stream>>>(x, wdw, bdw, gdw, bedw, mdw, vdw, w4, bs, gs, bes, ms, vs, z2s);
  kB<<<dim3(72, 4, 8), 256, 0, stream>>>(wopp, z2s, co, (float*)d_out);
}

// Round 11
// 122.519 us; speedup vs baseline: 2.3832x; 1.0140x over previous
//
#include <hip/hip_runtime.h>
#include <cstdint>
#include <cstddef>

typedef float  f32x4 __attribute__((ext_vector_type(4)));
typedef float  f32x2 __attribute__((ext_vector_type(2)));
typedef short  s16x8 __attribute__((ext_vector_type(8)));
typedef short  s16x4 __attribute__((ext_vector_type(4)));
typedef unsigned int u32x4 __attribute__((ext_vector_type(4)));

#define EPSV 1e-5f

__device__ __forceinline__ float rfl(float v) {
  return __builtin_bit_cast(float, __builtin_amdgcn_readfirstlane(__builtin_bit_cast(int, v)));
}
__device__ __forceinline__ unsigned pk2(float a, float b) {
  unsigned short ua = __builtin_bit_cast(unsigned short, (__bf16)a);
  unsigned short ub = __builtin_bit_cast(unsigned short, (__bf16)b);
  return (unsigned)ua | ((unsigned)ub << 16);
}
__device__ __forceinline__ void gll16(const void* g, void* l) {
  __builtin_amdgcn_global_load_lds((const __attribute__((address_space(1))) unsigned int*)g,
                                   (__attribute__((address_space(3))) unsigned int*)l, 16, 0, 0);
}
__device__ __forceinline__ f32x4 relu4(f32x4 v) {
  f32x4 r; r.x = fmaxf(v.x,0.f); r.y = fmaxf(v.y,0.f); r.z = fmaxf(v.z,0.f); r.w = fmaxf(v.w,0.f);
  return r;
}

// ---------------- kernel F: fold BN-o into Wo, emit bf16 in fragment layout ----------------
__global__ void kF(const float* __restrict__ wo, const float* __restrict__ bo,
                   const float* __restrict__ go, const float* __restrict__ beo,
                   const float* __restrict__ mo, const float* __restrict__ vo,
                   __bf16* __restrict__ wopp, float* __restrict__ co)
{
  const int oc = blockIdx.x;   // 0..511
  const int k  = threadIdx.x;  // 0..511
  float invo = go[oc] * rsqrtf(vo[oc] + EPSV);
  float v = wo[(size_t)oc*512 + k] * invo;
  int mt = oc >> 7, ocl = oc & 127;
  int kt = k >> 6, kk = (k >> 5) & 1, g = (k >> 3) & 3, jj = k & 7;
  size_t dst = (size_t)(mt*8 + kt)*10240 + (size_t)kk*5120 + ocl*40 + g*8 + jj;
  wopp[dst] = (__bf16)v;
  if (k == 0) co[oc] = bo[oc]*invo + beo[oc] - mo[oc]*invo;
}

// ---------------- kernel A: 4 dilated depthwise convs + BN + ReLU + 4x4 mix + BN + ReLU ----
// R10's proven-clean body (VGPR 40, zero spill, FETCH/WRITE 74 MB) + ONE delta:
// ANTI-PHASE DESYNC. R10 counters showed VALU(23us) + DS(29us) + HBM(24us) serial-summing
// to the measured 85us: a CU's 2 co-resident blocks arrive together, run identical code in
// lockstep, and contend for the same pipe in every phase (2x stretch each). Under
// round-robin dispatch CU c holds blocks {n, n+256}, so key=(blockIdx.x>>8)&1 splits the
// resident pair: key=1 blocks sleep ~2.5us once (~half a phase) => block B stages (HBM)
// while block A computes (DS/VALU), both at full rate. Bounded downside ~+3us if theory
// is wrong. Deterministic (fixed-length s_sleep), graph-safe.
__global__ __launch_bounds__(768, 6) void kA(const float* __restrict__ x,
    const float* __restrict__ wdw, const float* __restrict__ bdw, const float* __restrict__ gdw,
    const float* __restrict__ bedw, const float* __restrict__ mdw, const float* __restrict__ vdw,
    const float* __restrict__ w4, const float* __restrict__ bsc, const float* __restrict__ gsc,
    const float* __restrict__ besc, const float* __restrict__ msc, const float* __restrict__ vsc,
    __bf16* __restrict__ z2s)
{
  __shared__ alignas(16) float sp[96*136];   // 52224 B: row = 20 pad | 96 data | 20 slack
  const int tid = threadIdx.x;
  const int b = blockIdx.x >> 7, c = blockIdx.x & 127;

  if ((blockIdx.x >> 8) & 1) {               // half-phase lag for the co-resident partner
    __builtin_amdgcn_s_sleep(24);            // 4 x ~1536 cy  ~= 6150 cy ~= 2.56 us
    __builtin_amdgcn_s_sleep(24);
    __builtin_amdgcn_s_sleep(24);
    __builtin_amdgcn_s_sleep(24);
  }

  // uniform folded params (readfirstlane -> SGPRs)
  float wf[4][9], cdwv[4], w4f[4][4], c4v[4];
  #pragma unroll
  for (int i = 0; i < 4; ++i) {
    int idx = i*128 + c;
    float inv = gdw[idx] * rsqrtf(vdw[idx] + EPSV);
    #pragma unroll
    for (int t = 0; t < 9; ++t) wf[i][t] = rfl(wdw[(size_t)idx*9 + t] * inv);
    cdwv[i] = rfl(bdw[idx]*inv + bedw[idx] - mdw[idx]*inv);
  }
  #pragma unroll
  for (int o = 0; o < 4; ++o) {
    float invs = gsc[o] * rsqrtf(vsc[o] + EPSV);
    #pragma unroll
    for (int i = 0; i < 4; ++i) w4f[o][i] = rfl(w4[o*4 + i] * invs);
    c4v[o] = rfl(bsc[o]*invs + besc[o] - msc[o]*invs);
  }

  // zero the row pads once (stage writes only touch interior cols 20..115)
  for (int z = tid; z < 96*40; z += 768) {
    int row = z / 40, cw = z - row*40;
    sp[row*136 + (cw < 20 ? cw : 96 + cw)] = 0.f;
  }

  const int wq = tid % 24;
  const int hb = (tid / 24) * 3;      // 32 h-groups * 3 rows = 96, exact
  const int w0 = wq * 4;

  const f32x4* xv = (const f32x4*)x;
  const size_t gbase = (size_t)(b*512 + c) * 2304;   // f32x4 units; +i*294912 per branch

  // stage coords: element j = tid + k*768 -> (row, col-quad)
  const int s0r = tid / 24,          s0c = tid - s0r*24;
  const int s1r = (tid + 768) / 24,  s1c = (tid + 768) - s1r*24;
  const int s2r = (tid + 1536) / 24, s2c = (tid + 1536) - s2r*24;
  float* st0 = sp + s0r*136 + 20 + s0c*4;
  float* st1 = sp + s1r*136 + 20 + s1c*4;
  float* st2 = sp + s2r*136 + 20 + s2c*4;

  f32x4 zacc[4][3];
  #pragma unroll
  for (int o = 0; o < 4; ++o)
    #pragma unroll
    for (int k = 0; k < 3; ++k)
      zacc[o][k] = (f32x4){c4v[o], c4v[o], c4v[o], c4v[o]};

  // prologue: stage plane 0 directly
  {
    f32x4 p0 = xv[gbase + tid];
    f32x4 p1 = xv[gbase + tid + 768];
    f32x4 p2 = xv[gbase + tid + 1536];
    *(f32x4*)st0 = p0;
    *(f32x4*)st1 = p1;
    *(f32x4*)st2 = p2;
  }
  __syncthreads();

  const int RR[4] = {1, 6, 12, 18};

  #pragma unroll
  for (int i = 0; i < 4; ++i) {
    // T14: issue next plane's loads BEFORE this plane's compute; latency hides under it
    f32x4 pf0, pf1, pf2;
    if (i < 3) {
      const size_t pb = gbase + (size_t)(i+1)*294912;
      pf0 = xv[pb + tid];
      pf1 = xv[pb + tid + 768];
      pf2 = xv[pb + tid + 1536];
      __builtin_amdgcn_sched_barrier(0);   // pin the loads above the compute
    }

    const int r = RR[i];
    #pragma unroll
    for (int k = 0; k < 3; ++k) {
      const int h = hb + k;
      f32x4 acc = {0.f, 0.f, 0.f, 0.f};
      #pragma unroll
      for (int dh = -1; dh <= 1; ++dh) {
        const int h2 = h + dh*r;
        if ((unsigned)h2 < 96u) {
          const float* row = sp + h2*136 + 20 + w0;
          f32x4 tc = *(const f32x4*)row;      // 16B-aligned
          f32x4 tl, tr;
          if (i == 0) {                        // r=1: two 8B edge reads + register compose
            f32x2 a  = *(const f32x2*)(row - 2);
            f32x2 bb = *(const f32x2*)(row + 4);
            tl = (f32x4){a.y, tc.x, tc.y, tc.z};
            tr = (f32x4){tc.y, tc.z, tc.w, bb.x};
          } else if (r == 12) {                // 16B-aligned
            tl = *(const f32x4*)(row - 12);
            tr = *(const f32x4*)(row + 12);
          } else {                             // r=6/18: 8B-aligned pairs
            f32x2 a0 = *(const f32x2*)(row - r), a1 = *(const f32x2*)(row - r + 2);
            f32x2 b0 = *(const f32x2*)(row + r), b1 = *(const f32x2*)(row + r + 2);
            tl = (f32x4){a0.x, a0.y, a1.x, a1.y};
            tr = (f32x4){b0.x, b0.y, b1.x, b1.y};
          }
          const int wb = (dh + 1) * 3;
          acc += wf[i][wb]*tl + wf[i][wb+1]*tc + wf[i][wb+2]*tr;
        }
      }
      f32x4 y = relu4(acc + cdwv[i]);
      #pragma unroll
      for (int o = 0; o < 4; ++o) zacc[o][k] += w4f[o][i]*y;
    }

    __syncthreads();                           // everyone done reading plane i
    if (i < 3) {
      *(f32x4*)st0 = pf0;                      // writes only; loads long landed
      *(f32x4*)st1 = pf1;
      *(f32x4*)st2 = pf2;
      __syncthreads();                         // plane i+1 ready
    }
  }

  // finalize + store: [pix][o], 16 bf16 = 32B contiguous per quad
  __bf16* zbase = z2s + (size_t)(b*128 + c) * 36864;
  #pragma unroll
  for (int k = 0; k < 3; ++k) {
    const int h = hb + k;
    f32x4 z[4];
    #pragma unroll
    for (int o = 0; o < 4; ++o) z[o] = relu4(zacc[o][k]);
    u32x4 s0 = { pk2(z[0].x,z[1].x), pk2(z[2].x,z[3].x), pk2(z[0].y,z[1].y), pk2(z[2].y,z[3].y) };
    u32x4 s1 = { pk2(z[0].z,z[1].z), pk2(z[2].z,z[3].z), pk2(z[0].w,z[1].w), pk2(z[2].w,z[3].w) };
    u32x4* dst = (u32x4*)(zbase + (size_t)(h*24 + wq)*16);
    dst[0] = s0;
    dst[1] = s1;
  }
}

// ---------------- kernel B: out = ReLU(Wo'' @ z2 + co), bf16 MFMA, m97 structure -----------
__global__ __launch_bounds__(256) void kB(const void* __restrict__ wopp_,
    const void* __restrict__ z2s_, const float* __restrict__ co, float* __restrict__ out)
{
  __shared__ alignas(16) char lA[20480];
  __shared__ alignas(16) char lB[16384];
  const char* wopp = (const char*)wopp_;
  const char* z2s  = (const char*)z2s_;

  const int tid = threadIdx.x;
  const int lane = tid & 63, wv = tid >> 6;
  const int wm = wv >> 1, wn = wv & 1;
  const int pt = blockIdx.x;      // 0..71 pixel tiles
  const int mt = blockIdx.y;      // 0..3  oc tiles
  const int b  = blockIdx.z;      // 0..7
  const int pix0 = pt * 128;
  const int l15 = lane & 15, lg = lane >> 4;

  f32x4 acc[4][4] = {};

  for (int kt = 0; kt < 8; ++kt) {
    const char* srcA = wopp + (size_t)(mt*8 + kt)*20480;
    for (int j = wv; j < 20; j += 4)
      gll16(srcA + j*1024 + lane*16, lA + j*1024);
    #pragma unroll
    for (int ct4 = 0; ct4 < 4; ++ct4) {
      int ct = wv*4 + ct4;
      const char* srcB = z2s + ((size_t)(b*128 + kt*16 + ct)*36864 + (size_t)pix0*4)*2;
      gll16(srcB + lane*16, lB + ct*1024);
    }
    __syncthreads();

    #pragma unroll
    for (int kk = 0; kk < 2; ++kk) {
      s16x8 af[4];
      #pragma unroll
      for (int m = 0; m < 4; ++m)
        af[m] = *(const s16x8*)(lA + kk*10240 + (wm*64 + m*16 + l15)*80 + lg*16);
      #pragma unroll
      for (int n = 0; n < 4; ++n) {
        const char* p = lB + kk*8192 + lg*2048 + (wn*64 + n*16 + l15)*8;
        s16x4 lo = *(const s16x4*)(p);
        s16x4 hi = *(const s16x4*)(p + 1024);
        s16x8 bfr = __builtin_shufflevector(lo, hi, 0,1,2,3,4,5,6,7);
        #pragma unroll
        for (int m = 0; m < 4; ++m)
          acc[m][n] = __builtin_amdgcn_mfma_f32_16x16x32_bf16(af[m], bfr, acc[m][n], 0, 0, 0);
      }
    }
    __syncthreads();
  }

  const int colp = pix0 + wn*64 + l15;
  #pragma unroll
  for (int m = 0; m < 4; ++m) {
    const int ocb = mt*128 + wm*64 + m*16 + lg*4;
    #pragma unroll
    for (int r2 = 0; r2 < 4; ++r2) {
      const int oc = ocb + r2;
      const float cov = co[oc];
      float* orow = out + ((size_t)(b*512 + oc))*9216 + colp;
      #pragma unroll
      for (int n = 0; n < 4; ++n) {
        float v = acc[m][n][r2] + cov;
        orow[(size_t)n*16] = fmaxf(v, 0.f);
      }
    }
  }
}

extern "C" void kernel_launch(void* const* d_in, const int* in_sizes, int n_in,
                              void* d_out, int out_size, void* d_ws, size_t ws_size,
                              hipStream_t stream)
{
  (void)in_sizes; (void)out_size;
  if (n_in < 19) return;
  const size_t Z2_BYTES = 75497472;      // 8*512*9216 bf16
  const size_t WOPP_BYTES = 655360;      // 32 chunks * 20480
  if (ws_size < Z2_BYTES + WOPP_BYTES + 2048) return;

  const float* x    = (const float*)d_in[0];
  const float* wdw  = (const float*)d_in[1];
  const float* bdw  = (const float*)d_in[2];
  const float* gdw  = (const float*)d_in[3];
  const float* bedw = (const float*)d_in[4];
  const float* mdw  = (const float*)d_in[5];
  const float* vdw  = (const float*)d_in[6];
  const float* w4   = (const float*)d_in[7];
  const float* bs   = (const float*)d_in[8];
  const float* gs   = (const float*)d_in[9];
  const float* bes  = (const float*)d_in[10];
  const float* ms   = (const float*)d_in[11];
  const float* vs   = (const float*)d_in[12];
  const float* wo   = (const float*)d_in[13];
  const float* bo   = (const float*)d_in[14];
  const float* go   = (const float*)d_in[15];
  const float* beo  = (const float*)d_in[16];
  const float* mo   = (const float*)d_in[17];
  const float* vo   = (const float*)d_in[18];

  __bf16* z2s  = (__bf16*)d_ws;
  __bf16* wopp = (__bf16*)((char*)d_ws + Z2_BYTES);
  float*  co   = (float*)((char*)d_ws + Z2_BYTES + WOPP_BYTES);

  kF<<<512, 512, 0, stream>>>(wo, bo, go, beo, mo, vo, wopp, co);
  kA<<<1024, 768, 0, stream>>>(x, wdw, bdw, gdw, bedw, mdw, vdw, w4, bs, gs, bes, ms, vs, z2s);
  kB<<<dim3(72, 4, 8), 256, 0, stream>>>(wopp, z2s, co, (float*)d_out);
}